// Round 13
// baseline (183.070 us; speedup 1.0000x reference)
//
#include <hip/hip_runtime.h>
#include <math.h>

#define S_LEN  1024
#define EMB    2048
#define NH_    8
#define DH_    256
#define TOKENS 2048   // B*S
#define NBH    16     // B*NH
#define NQKVO  4608   // 2048 q | 256 k | 256 v | 2048 o

typedef __attribute__((ext_vector_type(4))) float    f32x4;
typedef __attribute__((ext_vector_type(8))) _Float16 f16x8;
typedef __attribute__((ext_vector_type(4))) _Float16 f16x4;

__device__ __forceinline__ _Float16 f2h(float f) { return (_Float16)f; }

// async global->LDS, 16B per lane; LDS dest = wave-uniform base + lane*16
__device__ __forceinline__ void gload16(const void* g, void* l) {
  __builtin_amdgcn_global_load_lds(
      (const __attribute__((address_space(1))) void*)g,
      (__attribute__((address_space(3))) void*)l, 16, 0, 0);
}

// ---------------------------------------------------------------------------
// Merged prep: blocks [0,2048): x->xh cast + i/f gate projections;
// blocks [2048,5376): weight transposes (Wq,Wk,Wv,Wog->WcatT; Wout->WoutT).
// ---------------------------------------------------------------------------
__global__ __launch_bounds__(256) void prep_kernel(
    const float* __restrict__ x, const float* __restrict__ Wi, const float* __restrict__ bi,
    const float* __restrict__ Wf, const float* __restrict__ bfg,
    const float* __restrict__ Wq, const float* __restrict__ Wk,
    const float* __restrict__ Wv, const float* __restrict__ Wog,
    const float* __restrict__ Wout,
    _Float16* __restrict__ xh, float* __restrict__ ip, float* __restrict__ fp,
    _Float16* __restrict__ WcatT, _Float16* __restrict__ WoutT)
{
  __shared__ float shmem[64][65];
  int t = blockIdx.x;
  const int tid = threadIdx.x;
  if (t < TOKENS) {
    // ---- proj_if_cast ----
    const int tok = t;
    const float* xr = x + (long)tok * EMB;
    float ai[8] = {}, af[8] = {};
    #pragma unroll
    for (int j = 0; j < 8; ++j) {
      const int e = tid + j * 256;
      const float xe = xr[e];
      xh[(long)tok * EMB + e] = f2h(xe);
      const float4* wi4 = (const float4*)(Wi + (long)e * 8);
      const float4* wf4 = (const float4*)(Wf + (long)e * 8);
      const float4 a0 = wi4[0], a1 = wi4[1], b0 = wf4[0], b1 = wf4[1];
      ai[0] += xe * a0.x; ai[1] += xe * a0.y; ai[2] += xe * a0.z; ai[3] += xe * a0.w;
      ai[4] += xe * a1.x; ai[5] += xe * a1.y; ai[6] += xe * a1.z; ai[7] += xe * a1.w;
      af[0] += xe * b0.x; af[1] += xe * b0.y; af[2] += xe * b0.z; af[3] += xe * b0.w;
      af[4] += xe * b1.x; af[5] += xe * b1.y; af[6] += xe * b1.z; af[7] += xe * b1.w;
    }
    #pragma unroll
    for (int hh = 0; hh < 8; ++hh)
      for (int off = 32; off; off >>= 1) {
        ai[hh] += __shfl_xor(ai[hh], off);
        af[hh] += __shfl_xor(af[hh], off);
      }
    float (*red)[16] = (float(*)[16])shmem;
    const int lane = tid & 63, wid = tid >> 6;
    if (lane == 0) {
      #pragma unroll
      for (int hh = 0; hh < 8; ++hh) { red[wid][hh] = ai[hh]; red[wid][hh + 8] = af[hh]; }
    }
    __syncthreads();
    if (tid < 16) {
      const float v = red[0][tid] + red[1][tid] + red[2][tid] + red[3][tid];
      const int b = tok >> 10, s = tok & 1023;
      if (tid < 8) {
        const float zv = v + bi[tid];
        ip[(long)(b * NH_ + tid) * S_LEN + s] = 15.0f * tanhf(zv * (1.0f / 15.0f));
      } else {
        const int hh = tid - 8;
        const float zv = v + bfg[hh];
        fp[(long)(b * NH_ + hh) * S_LEN + s] = 15.0f * tanhf(zv * (1.0f / 15.0f));
      }
    }
  } else {
    // ---- weight transposes ----
    t -= TOKENS;
    const float* in; _Float16* out; int ldi, ct;
    if (t < 1024)      { in = Wq;   out = WcatT;                    ldi = 2048; ct = 32; }
    else if (t < 1152) { t -= 1024; in = Wk;  out = WcatT + (long)2048 * EMB; ldi = 256; ct = 4; }
    else if (t < 1280) { t -= 1152; in = Wv;  out = WcatT + (long)2304 * EMB; ldi = 256; ct = 4; }
    else if (t < 2304) { t -= 1280; in = Wog; out = WcatT + (long)2560 * EMB; ldi = 2048; ct = 32; }
    else               { t -= 2304; in = Wout; out = WoutT;         ldi = 2048; ct = 32; }
    const long c0 = (long)(t % ct) * 64, r0 = (long)(t / ct) * 64;
    const int lx = tid & 63, ly = tid >> 6;
    #pragma unroll
    for (int i = 0; i < 16; ++i)
      shmem[ly + i * 4][lx] = in[(r0 + ly + i * 4) * ldi + c0 + lx];
    __syncthreads();
    #pragma unroll
    for (int i = 0; i < 16; ++i)
      out[(c0 + ly + i * 4) * EMB + r0 + lx] = f2h(shmem[lx][ly + i * 4]);
  }
}

// ---------------------------------------------------------------------------
// Tiled transpose + cast to f16 (f16 input path used for V^T).
// ---------------------------------------------------------------------------
template<typename TIN>
__global__ __launch_bounds__(256) void transpose_cast_kernel(
    const TIN* __restrict__ in, long ldi, _Float16* __restrict__ out, long ldo,
    long sIn, long sOut)
{
  __shared__ float t[64][65];
  const int lx = threadIdx.x & 63, ly = threadIdx.x >> 6;
  const long r0 = (long)blockIdx.y * 64, c0 = (long)blockIdx.x * 64;
  const TIN* ip = in + (long)blockIdx.z * sIn;
  _Float16* op = out + (long)blockIdx.z * sOut;
  #pragma unroll
  for (int i = 0; i < 16; ++i)
    t[ly + i * 4][lx] = (float)ip[(r0 + ly + i * 4) * ldi + c0 + lx];
  __syncthreads();
  #pragma unroll
  for (int i = 0; i < 16; ++i)
    op[(c0 + ly + i * 4) * ldo + r0 + lx] = f2h(t[lx][ly + i * 4]);
}

// ---------------------------------------------------------------------------
// f16 GEMM, BMx128 tile, BK=32, 4 waves, 3-deep prefetch.
// R13: ONE barrier per K-step.  Stage(t) fills buf[(t+2)%3], last read at
// t-1; every wave's t-1 ds_reads landed in regs before it reaches barrier t
// (compiler lgkmcnt precedes consuming MFMAs), so issuing the stage AFTER
// the barrier is race-free and the trailing barrier is dropped.  Counted
// vmcnt re-derived for this order: only stage(t-1)'s L loads follow the
// stage that filled buf[t%3]  =>  vmcnt(L) steady / vmcnt(0) last step.
// L = BM/64 + 2 loads/thread/stage (4 for BM=128, 3 for BM=64).
// XOR-swizzled LDS (conflict-free R6); bijective XCD swizzle.
// ---------------------------------------------------------------------------
template<typename CT, int BM>
__global__ __launch_bounds__(256) void gemm_bt_kernel(
    const _Float16* __restrict__ Ag, const _Float16* __restrict__ Btg,
    CT* __restrict__ Cg, int K, int lda, int ldb, int ldc,
    long sA, long sB, long sC, int zdivB, int mtiles, int causal)
{
  constexpr int MR = BM / 32;
  __shared__ _Float16 As[3][BM * 32];
  __shared__ _Float16 Bs[3][128 * 32];
  const int tid = threadIdx.x;
  const int lane = tid & 63, wid = tid >> 6;
  const int cpx = gridDim.x >> 3;
  const int wg = ((int)blockIdx.x & 7) * cpx + ((int)blockIdx.x >> 3);
  const int m0 = (wg % mtiles) * BM;
  const int n0 = (wg / mtiles) * 128;
  const int z  = blockIdx.z;
  const _Float16* Ap = Ag + (long)z * sA + (long)m0 * lda;
  const _Float16* Bp = Btg + (long)(z / zdivB) * sB + (long)n0 * ldb;
  const int wr = wid >> 1, wc = wid & 1;
  const int lrow = lane & 15, kseg = lane >> 4;
  const int kl = causal ? ((m0 + BM < K) ? m0 + BM : K) : K;

  auto stage = [&](int b, int k0) {
    #pragma unroll
    for (int i = 0; i < BM / 64; ++i) {
      const int cbase = (i * 4 + wid) * 64;
      const int row = (cbase >> 2) + (lane >> 2);
      const int src = ((lane & 3) ^ ((row >> 1) & 3)) * 8;
      gload16(Ap + (long)row * lda + k0 + src, (char*)As[b] + cbase * 16);
    }
    #pragma unroll
    for (int i = 0; i < 2; ++i) {
      const int cbase = (i * 4 + wid) * 64;
      const int row = (cbase >> 2) + (lane >> 2);
      const int src = ((lane & 3) ^ ((row >> 1) & 3)) * 8;
      gload16(Bp + (long)row * ldb + k0 + src, (char*)Bs[b] + cbase * 16);
    }
  };

  const int nt = kl >> 5;
  f32x4 acc[MR][4] = {};
  stage(0, 0);
  if (nt > 1) stage(1, 32);
  for (int t = 0; t < nt; ++t) {
    if (t + 1 < nt) {
      if constexpr (BM == 128) asm volatile("s_waitcnt vmcnt(4)" ::: "memory");
      else                     asm volatile("s_waitcnt vmcnt(3)" ::: "memory");
    } else {
      asm volatile("s_waitcnt vmcnt(0)" ::: "memory");
    }
    __builtin_amdgcn_s_barrier();
    __builtin_amdgcn_sched_barrier(0);
    if (t + 2 < nt) stage((t + 2) % 3, (t + 2) * 32);  // after barrier: all t-1 reads done
    const int buf = t % 3;
    f16x8 fa[MR], fb[4];
    #pragma unroll
    for (int m = 0; m < MR; ++m) {
      const int row = wr * (BM / 2) + m * 16 + lrow;
      fa[m] = *(const f16x8*)&As[buf][row * 32 + ((kseg ^ ((row >> 1) & 3)) << 3)];
    }
    #pragma unroll
    for (int n = 0; n < 4; ++n) {
      const int row = wc * 64 + n * 16 + lrow;
      fb[n] = *(const f16x8*)&Bs[buf][row * 32 + ((kseg ^ ((row >> 1) & 3)) << 3)];
    }
    #pragma unroll
    for (int m = 0; m < MR; ++m)
      #pragma unroll
      for (int n = 0; n < 4; ++n)
        acc[m][n] = __builtin_amdgcn_mfma_f32_16x16x32_f16(fa[m], fb[n], acc[m][n], 0, 0, 0);
    // no trailing barrier: next iteration's leading barrier orders the overwrite
  }
  CT* Cp = Cg + (long)z * sC;
  #pragma unroll
  for (int m = 0; m < MR; ++m)
    #pragma unroll
    for (int n = 0; n < 4; ++n)
      #pragma unroll
      for (int i = 0; i < 4; ++i) {
        const int r = m0 + wr * (BM / 2) + m * 16 + kseg * 4 + i;  // row=(lane>>4)*4+i (m89)
        const int c = n0 + wc * 64 + n * 16 + lrow;                // col=lane&15
        Cp[(long)r * ldc + c] = (CT)acc[m][n][i];
      }
}

// ---------------------------------------------------------------------------
// Per (b,h): logsigmoid, cumsum cf, a = i_pre - cf, running max m, vecM = cf+m.
// ---------------------------------------------------------------------------
__global__ __launch_bounds__(1024) void gates_kernel(
    const float* __restrict__ fp, const float* __restrict__ ip,
    float* __restrict__ aArr, float* __restrict__ mArr, float* __restrict__ vMArr)
{
  const int bh = blockIdx.x;
  const int s = threadIdx.x;
  __shared__ float sh[1024];
  const float f = fp[(long)bh * S_LEN + s];
  const float lsg = fminf(f, 0.0f) - log1pf(expf(-fabsf(f)));  // log_sigmoid
  float v = lsg;
  sh[s] = v; __syncthreads();
  for (int off = 1; off < 1024; off <<= 1) {
    const float o = (s >= off) ? sh[s - off] : 0.0f;
    __syncthreads();
    v += o; sh[s] = v;
    __syncthreads();
  }
  const float cf = v;
  const float a = ip[(long)bh * S_LEN + s] - cf;
  v = a;
  sh[s] = v; __syncthreads();
  for (int off = 1; off < 1024; off <<= 1) {
    const float o = (s >= off) ? sh[s - off] : -3.0e38f;
    __syncthreads();
    v = fmaxf(v, o); sh[s] = v;
    __syncthreads();
  }
  aArr[(long)bh * S_LEN + s] = a;
  mArr[(long)bh * S_LEN + s] = v;
  vMArr[(long)bh * S_LEN + s] = cf + v;
}

// ---------------------------------------------------------------------------
// Fused mLSTM attention, triangle-paired, QBLK=32, 512 threads / 8 waves
// (R11 config: 2 waves/SIMD, K/V frags global->reg with reg pipelining).
// ---------------------------------------------------------------------------
__global__ __launch_bounds__(512) void att_fused_kernel(
    const _Float16* __restrict__ qkvo, const _Float16* __restrict__ vt,
    const float* __restrict__ aArr, const float* __restrict__ mArr,
    const float* __restrict__ vMArr, _Float16* __restrict__ hb)
{
  __shared__ _Float16 Qs[2][32 * 256];   // swizzled: 32 chunks/row, ^(row&7)
  __shared__ _Float16 Ws[2][32 * 128];   // swizzled: 16 chunks/row, ^((row&7)<<1)
  __shared__ float nsh[2][8][32];
  __shared__ float invs[2][32];
  const int tid = threadIdx.x;
  const int lane = tid & 63, wid = tid >> 6;     // 8 waves
  const int bh = blockIdx.y;
  const int b = bh >> 3, h = bh & 7;
  const int r0[2] = { (int)blockIdx.x * 32, (31 - (int)blockIdx.x) * 32 };
  const _Float16* Qg = qkvo + (long)(b * S_LEN) * NQKVO + h * DH_;
  const _Float16* Kg = qkvo + (long)(b * S_LEN) * NQKVO + 2048;
  const _Float16* Vt = vt + (long)b * DH_ * S_LEN;
  const float* aA = aArr + (long)bh * S_LEN;
  const float* mA = mArr + (long)bh * S_LEN;
  const int lrow = lane & 15, kseg = lane >> 4;
  const int tbase = 16 * wid;                    // QK t-slice per wave
  const int dbase = 32 * wid;                    // PV d-slice per wave

  #pragma unroll
  for (int i = 0; i < 4; ++i) {
    const int cbase = (i * 8 + wid) * 64;        // wave-uniform
    const int c = cbase + lane;
    const int sub = c >> 10, row = (c >> 5) & 31, slot = c & 31;
    gload16(Qg + (long)(r0[sub] + row) * NQKVO + (slot ^ (row & 7)) * 8,
            (char*)Qs + cbase * 16);
  }

  float m_s[2][2][4];
  #pragma unroll
  for (int sub = 0; sub < 2; ++sub)
    #pragma unroll
    for (int m = 0; m < 2; ++m)
      #pragma unroll
      for (int i = 0; i < 4; ++i)
        m_s[sub][m][i] = mA[r0[sub] + m * 16 + kseg * 4 + i];
  __syncthreads();   // Q staged (drains vmcnt)

  f32x4 hacc[2][2][2] = {};
  float nacc[2][2][4] = {};
  for (int n0 = 0; n0 <= r0[1]; n0 += 128) {
    // ---- QK^T: 1 K-frag per wave (16 t-cols), next-step reg prefetch ----
    f32x4 acc[2][2] = {};
    f16x8 fb, fbn;
    fb = *(const f16x8*)(Kg + (long)(n0 + tbase + lrow) * NQKVO + kseg * 8);
    #pragma unroll
    for (int k0 = 0; k0 < DH_; k0 += 32) {
      if (k0 + 32 < DH_)
        fbn = *(const f16x8*)(Kg + (long)(n0 + tbase + lrow) * NQKVO + k0 + 32 + kseg * 8);
      const int chunk = (k0 >> 3) + kseg;
      __builtin_amdgcn_s_setprio(1);
      #pragma unroll
      for (int sub = 0; sub < 2; ++sub) {
        if (n0 > r0[sub]) continue;
        #pragma unroll
        for (int m = 0; m < 2; ++m) {
          const int qrow = m * 16 + lrow;
          const f16x8 fa = *(const f16x8*)&Qs[sub][qrow * 256 + ((chunk ^ (qrow & 7)) << 3)];
          acc[sub][m] = __builtin_amdgcn_mfma_f32_16x16x32_f16(fa, fb, acc[sub][m], 0, 0, 0);
        }
      }
      __builtin_amdgcn_s_setprio(0);
      fb = fbn;
    }
    // ---- weighting -> Ws (swizzled), row-sum accumulation ----
    const float a_t = aA[n0 + tbase + lrow];
    #pragma unroll
    for (int sub = 0; sub < 2; ++sub) {
      if (n0 > r0[sub]) continue;
      #pragma unroll
      for (int m = 0; m < 2; ++m)
        #pragma unroll
        for (int i = 0; i < 4; ++i) {
          const int sr = m * 16 + kseg * 4 + i;     // local row 0..31
          const int t  = tbase + lrow;              // local col 0..127
          float w = 0.0f;
          if (n0 + t <= r0[sub] + sr)
            w = acc[sub][m][i] * 0.0625f * expf(a_t - m_s[sub][m][i]);
          nacc[sub][m][i] += w;
          Ws[sub][sr * 128 + (((t >> 3) ^ ((sr & 7) << 1)) << 3) + (t & 7)] = f2h(w);
        }
    }
    // ---- issue-early V loads for kt=0 ----
    f16x8 vb[2], vbn[2];
    #pragma unroll
    for (int n = 0; n < 2; ++n)
      vb[n] = *(const f16x8*)(Vt + (long)(dbase + n * 16 + lrow) * S_LEN + n0 + kseg * 8);
    __syncthreads();
    // ---- PV: Ws from LDS, V frags pipelined ----
    #pragma unroll
    for (int kt = 0; kt < 128; kt += 32) {
      if (kt + 32 < 128) {
        #pragma unroll
        for (int n = 0; n < 2; ++n)
          vbn[n] = *(const f16x8*)(Vt + (long)(dbase + n * 16 + lrow) * S_LEN + n0 + kt + 32 + kseg * 8);
      }
      const int chunk = (kt >> 3) + kseg;
      __builtin_amdgcn_s_setprio(1);
      #pragma unroll
      for (int sub = 0; sub < 2; ++sub) {
        if (n0 > r0[sub]) continue;
        #pragma unroll
        for (int m = 0; m < 2; ++m) {
          const int row = m * 16 + lrow;
          const f16x8 wa = *(const f16x8*)&Ws[sub][row * 128 + ((chunk ^ ((row & 7) << 1)) << 3)];
          #pragma unroll
          for (int n = 0; n < 2; ++n)
            hacc[sub][m][n] = __builtin_amdgcn_mfma_f32_16x16x32_f16(wa, vb[n], hacc[sub][m][n], 0, 0, 0);
        }
      }
      __builtin_amdgcn_s_setprio(0);
      vb[0] = vbn[0]; vb[1] = vbn[1];
    }
    __syncthreads();   // Ws reads done before next pass overwrites
  }
  // ---- row sums -> invn ----
  #pragma unroll
  for (int sub = 0; sub < 2; ++sub)
    #pragma unroll
    for (int m = 0; m < 2; ++m)
      #pragma unroll
      for (int i = 0; i < 4; ++i) {
        float v = nacc[sub][m][i];
        v += __shfl_xor(v, 1); v += __shfl_xor(v, 2);
        v += __shfl_xor(v, 4); v += __shfl_xor(v, 8);
        if (lrow == 0) nsh[sub][wid][m * 16 + kseg * 4 + i] = v;
      }
  __syncthreads();
  if (tid < 64) {
    const int sub = tid >> 5, sr = tid & 31;
    float tot = 0.0f;
    #pragma unroll
    for (int w = 0; w < 8; ++w) tot += nsh[sub][w][sr];
    const float vm = vMArr[(long)bh * S_LEN + r0[sub] + sr];
    const float vecN = fmaxf(fabsf(tot), expf(-vm));
    invs[sub][sr] = 1.0f / (vecN + 1e-6f);
  }
  __syncthreads();
  #pragma unroll
  for (int sub = 0; sub < 2; ++sub)
    #pragma unroll
    for (int m = 0; m < 2; ++m)
      #pragma unroll
      for (int n = 0; n < 2; ++n)
        #pragma unroll
        for (int i = 0; i < 4; ++i) {
          const int row = m * 16 + kseg * 4 + i;
          const int d = dbase + n * 16 + lrow;
          hb[((long)bh * S_LEN + r0[sub] + row) * DH_ + d] = f2h(hacc[sub][m][n][i] * invs[sub][row]);
        }
}

// ---------------------------------------------------------------------------
// One wave per (token, head) row: LN over DH=256 (f32), *gamma, *sigmoid(o).
// ---------------------------------------------------------------------------
__global__ __launch_bounds__(256) void ln_gate_kernel(
    const _Float16* __restrict__ hbuf,
    const _Float16* __restrict__ qkvo, const float* __restrict__ gamma,
    _Float16* __restrict__ u)
{
  const int wid = threadIdx.x >> 6, lane = threadIdx.x & 63;
  const int row = blockIdx.x * 4 + wid;   // row = tok*8 + h
  const int tok = row >> 3, h = row & 7;
  const int b = tok >> 10, s = tok & 1023;
  const int bh = b * NH_ + h;
  const f16x4 hv = *(const f16x4*)(hbuf + ((long)bh * S_LEN + s) * DH_ + lane * 4);
  const float v0 = (float)hv[0], v1 = (float)hv[1], v2 = (float)hv[2], v3 = (float)hv[3];
  float s1 = v0 + v1 + v2 + v3;
  float s2 = v0 * v0 + v1 * v1 + v2 * v2 + v3 * v3;
  for (int off = 32; off; off >>= 1) { s1 += __shfl_xor(s1, off); s2 += __shfl_xor(s2, off); }
  const float mu = s1 * (1.0f / 256.0f);
  const float var = s2 * (1.0f / 256.0f) - mu * mu;
  const float rs = rsqrtf(var + 1e-6f);
  const float4 g = *(const float4*)(gamma + h * DH_ + lane * 4);
  const f16x4 ov = *(const f16x4*)(qkvo + (long)tok * NQKVO + 2560 + h * DH_ + lane * 4);
  f16x4 res;
  res[0] = f2h((v0 - mu) * rs * g.x * (1.0f / (1.0f + expf(-(float)ov[0]))));
  res[1] = f2h((v1 - mu) * rs * g.y * (1.0f / (1.0f + expf(-(float)ov[1]))));
  res[2] = f2h((v2 - mu) * rs * g.z * (1.0f / (1.0f + expf(-(float)ov[2]))));
  res[3] = f2h((v3 - mu) * rs * g.w * (1.0f / (1.0f + expf(-(float)ov[3]))));
  *(f16x4*)(u + (long)tok * EMB + h * DH_ + lane * 4) = res;
}

// ---------------------------------------------------------------------------
extern "C" void kernel_launch(void* const* d_in, const int* in_sizes, int n_in,
                              void* d_out, int out_size, void* d_ws, size_t ws_size,
                              hipStream_t stream)
{
  (void)in_sizes; (void)n_in; (void)out_size; (void)ws_size;
  const float* x     = (const float*)d_in[0];
  const float* Wq    = (const float*)d_in[1];
  const float* Wk    = (const float*)d_in[2];
  const float* Wv    = (const float*)d_in[3];
  const float* Wog   = (const float*)d_in[4];
  const float* Wi    = (const float*)d_in[5];
  const float* bi    = (const float*)d_in[6];
  const float* Wf    = (const float*)d_in[7];
  const float* bfg   = (const float*)d_in[8];
  const float* gamma = (const float*)d_in[9];
  const float* Wout  = (const float*)d_in[10];

  char* base = (char*)d_ws;
  size_t off = 0;
  auto take = [&](size_t bytes) -> char* {
    char* p = base + off;
    off += (bytes + 255) & ~(size_t)255;
    return p;
  };
  _Float16* xh    = (_Float16*)take((size_t)TOKENS * EMB * 2);        //  8 MB
  _Float16* WcatT = (_Float16*)take((size_t)NQKVO * EMB * 2);         // 19 MB
  _Float16* WoutT = (_Float16*)take((size_t)EMB * EMB * 2);           //  8 MB
  _Float16* qkvo  = (_Float16*)take((size_t)TOKENS * NQKVO * 2);      // 19 MB
  _Float16* vt    = (_Float16*)take((size_t)2 * DH_ * S_LEN * 2);     //  1 MB
  _Float16* hb    = (_Float16*)take((size_t)NBH * S_LEN * DH_ * 2);   //  8 MB
  float*    ip    = (float*)take((size_t)NBH * S_LEN * 4);
  float*    fp    = (float*)take((size_t)NBH * S_LEN * 4);
  float*    aA    = (float*)take((size_t)NBH * S_LEN * 4);
  float*    mA    = (float*)take((size_t)NBH * S_LEN * 4);
  float*    vM    = (float*)take((size_t)NBH * S_LEN * 4);
  _Float16* ub    = xh;   // xh dead after QKVO GEMM
  float*    y     = (float*)d_out;

  const dim3 blk(256);
  // --- merged prep: x cast + i/f projections + all weight transposes ---
  prep_kernel<<<dim3(TOKENS + 3328), blk, 0, stream>>>(
      x, Wi, bi, Wf, bfg, Wq, Wk, Wv, Wog, Wout, xh, ip, fp, WcatT, WoutT);
  // --- fused QKVO projection: [2048,4608] = xh @ WcatT^T (576 blocks) ---
  gemm_bt_kernel<_Float16, 128><<<dim3(36 * 16), blk, 0, stream>>>(
      xh, WcatT, qkvo, EMB, EMB, EMB, NQKVO, 0L, 0L, 0L, 1, 16, 0);
  // --- V^T per batch ---
  transpose_cast_kernel<_Float16><<<dim3(4, 16, 2), blk, 0, stream>>>(
      qkvo + 2304, NQKVO, vt, S_LEN, (long)S_LEN * NQKVO, (long)DH_ * S_LEN);
  // --- gates ---
  gates_kernel<<<dim3(NBH), dim3(1024), 0, stream>>>(fp, ip, aA, mA, vM);
  // --- fused mLSTM backend (QBLK=32 pairs, 256 blocks x 8 waves) ---
  att_fused_kernel<<<dim3(16, NBH), dim3(512), 0, stream>>>(qkvo, vt, aA, mA, vM, hb);
  // --- layernorm + output gate ---
  ln_gate_kernel<<<dim3(TOKENS * NH_ / 4), blk, 0, stream>>>(hb, qkvo, gamma, ub);
  // --- output projection: BM=64, 512 blocks -> 4 blocks/CU ---
  gemm_bt_kernel<float, 64><<<dim3(32 * 16), blk, 0, stream>>>(
      ub, WoutT, y, EMB, EMB, EMB, EMB, 0L, 0L, 0L, 1, 32, 0);
}

// Round 14
// 179.242 us; speedup vs baseline: 1.0214x; 1.0214x over previous
//
#include <hip/hip_runtime.h>
#include <math.h>

#define S_LEN  1024
#define EMB    2048
#define NH_    8
#define DH_    256
#define TOKENS 2048   // B*S
#define NBH    16     // B*NH
#define NQKVO  4608   // 2048 q | 256 k | 256 v | 2048 o

typedef __attribute__((ext_vector_type(4))) float    f32x4;
typedef __attribute__((ext_vector_type(8))) _Float16 f16x8;
typedef __attribute__((ext_vector_type(4))) _Float16 f16x4;

__device__ __forceinline__ _Float16 f2h(float f) { return (_Float16)f; }

// async global->LDS, 16B per lane; LDS dest = wave-uniform base + lane*16
__device__ __forceinline__ void gload16(const void* g, void* l) {
  __builtin_amdgcn_global_load_lds(
      (const __attribute__((address_space(1))) void*)g,
      (__attribute__((address_space(3))) void*)l, 16, 0, 0);
}

// ---------------------------------------------------------------------------
// Merged prep: blocks [0,2048): x->xh cast + i/f gate projections;
// blocks [2048,5376): weight transposes (Wq,Wk,Wv,Wog->WcatT; Wout->WoutT).
// ---------------------------------------------------------------------------
__global__ __launch_bounds__(256) void prep_kernel(
    const float* __restrict__ x, const float* __restrict__ Wi, const float* __restrict__ bi,
    const float* __restrict__ Wf, const float* __restrict__ bfg,
    const float* __restrict__ Wq, const float* __restrict__ Wk,
    const float* __restrict__ Wv, const float* __restrict__ Wog,
    const float* __restrict__ Wout,
    _Float16* __restrict__ xh, float* __restrict__ ip, float* __restrict__ fp,
    _Float16* __restrict__ WcatT, _Float16* __restrict__ WoutT)
{
  __shared__ float shmem[64][65];
  int t = blockIdx.x;
  const int tid = threadIdx.x;
  if (t < TOKENS) {
    // ---- proj_if_cast ----
    const int tok = t;
    const float* xr = x + (long)tok * EMB;
    float ai[8] = {}, af[8] = {};
    #pragma unroll
    for (int j = 0; j < 8; ++j) {
      const int e = tid + j * 256;
      const float xe = xr[e];
      xh[(long)tok * EMB + e] = f2h(xe);
      const float4* wi4 = (const float4*)(Wi + (long)e * 8);
      const float4* wf4 = (const float4*)(Wf + (long)e * 8);
      const float4 a0 = wi4[0], a1 = wi4[1], b0 = wf4[0], b1 = wf4[1];
      ai[0] += xe * a0.x; ai[1] += xe * a0.y; ai[2] += xe * a0.z; ai[3] += xe * a0.w;
      ai[4] += xe * a1.x; ai[5] += xe * a1.y; ai[6] += xe * a1.z; ai[7] += xe * a1.w;
      af[0] += xe * b0.x; af[1] += xe * b0.y; af[2] += xe * b0.z; af[3] += xe * b0.w;
      af[4] += xe * b1.x; af[5] += xe * b1.y; af[6] += xe * b1.z; af[7] += xe * b1.w;
    }
    #pragma unroll
    for (int hh = 0; hh < 8; ++hh)
      for (int off = 32; off; off >>= 1) {
        ai[hh] += __shfl_xor(ai[hh], off);
        af[hh] += __shfl_xor(af[hh], off);
      }
    float (*red)[16] = (float(*)[16])shmem;
    const int lane = tid & 63, wid = tid >> 6;
    if (lane == 0) {
      #pragma unroll
      for (int hh = 0; hh < 8; ++hh) { red[wid][hh] = ai[hh]; red[wid][hh + 8] = af[hh]; }
    }
    __syncthreads();
    if (tid < 16) {
      const float v = red[0][tid] + red[1][tid] + red[2][tid] + red[3][tid];
      const int b = tok >> 10, s = tok & 1023;
      if (tid < 8) {
        const float zv = v + bi[tid];
        ip[(long)(b * NH_ + tid) * S_LEN + s] = 15.0f * tanhf(zv * (1.0f / 15.0f));
      } else {
        const int hh = tid - 8;
        const float zv = v + bfg[hh];
        fp[(long)(b * NH_ + hh) * S_LEN + s] = 15.0f * tanhf(zv * (1.0f / 15.0f));
      }
    }
  } else {
    // ---- weight transposes ----
    t -= TOKENS;
    const float* in; _Float16* out; int ldi, ct;
    if (t < 1024)      { in = Wq;   out = WcatT;                    ldi = 2048; ct = 32; }
    else if (t < 1152) { t -= 1024; in = Wk;  out = WcatT + (long)2048 * EMB; ldi = 256; ct = 4; }
    else if (t < 1280) { t -= 1152; in = Wv;  out = WcatT + (long)2304 * EMB; ldi = 256; ct = 4; }
    else if (t < 2304) { t -= 1280; in = Wog; out = WcatT + (long)2560 * EMB; ldi = 2048; ct = 32; }
    else               { t -= 2304; in = Wout; out = WoutT;         ldi = 2048; ct = 32; }
    const long c0 = (long)(t % ct) * 64, r0 = (long)(t / ct) * 64;
    const int lx = tid & 63, ly = tid >> 6;
    #pragma unroll
    for (int i = 0; i < 16; ++i)
      shmem[ly + i * 4][lx] = in[(r0 + ly + i * 4) * ldi + c0 + lx];
    __syncthreads();
    #pragma unroll
    for (int i = 0; i < 16; ++i)
      out[(c0 + ly + i * 4) * EMB + r0 + lx] = f2h(shmem[lx][ly + i * 4]);
  }
}

// ---------------------------------------------------------------------------
// Tiled transpose + cast to f16 (f16 input path used for V^T).
// ---------------------------------------------------------------------------
template<typename TIN>
__global__ __launch_bounds__(256) void transpose_cast_kernel(
    const TIN* __restrict__ in, long ldi, _Float16* __restrict__ out, long ldo,
    long sIn, long sOut)
{
  __shared__ float t[64][65];
  const int lx = threadIdx.x & 63, ly = threadIdx.x >> 6;
  const long r0 = (long)blockIdx.y * 64, c0 = (long)blockIdx.x * 64;
  const TIN* ip = in + (long)blockIdx.z * sIn;
  _Float16* op = out + (long)blockIdx.z * sOut;
  #pragma unroll
  for (int i = 0; i < 16; ++i)
    t[ly + i * 4][lx] = (float)ip[(r0 + ly + i * 4) * ldi + c0 + lx];
  __syncthreads();
  #pragma unroll
  for (int i = 0; i < 16; ++i)
    op[(c0 + ly + i * 4) * ldo + r0 + lx] = f2h(t[lx][ly + i * 4]);
}

// ---------------------------------------------------------------------------
// f16 GEMM, BMx128 tile, BK=32, 4 waves, 3-deep prefetch (R12 proven loop:
// stage BEFORE vmcnt wait, two barriers — R13's 1-barrier variant regressed
// by delaying load issue).  XOR-swizzled LDS; bijective XCD swizzle.
// ---------------------------------------------------------------------------
template<typename CT, int BM>
__global__ __launch_bounds__(256) void gemm_bt_kernel(
    const _Float16* __restrict__ Ag, const _Float16* __restrict__ Btg,
    CT* __restrict__ Cg, int K, int lda, int ldb, int ldc,
    long sA, long sB, long sC, int zdivB, int mtiles, int causal)
{
  constexpr int MR = BM / 32;
  __shared__ _Float16 As[3][BM * 32];
  __shared__ _Float16 Bs[3][128 * 32];
  const int tid = threadIdx.x;
  const int lane = tid & 63, wid = tid >> 6;
  const int cpx = gridDim.x >> 3;
  const int wg = ((int)blockIdx.x & 7) * cpx + ((int)blockIdx.x >> 3);
  const int m0 = (wg % mtiles) * BM;
  const int n0 = (wg / mtiles) * 128;
  const int z  = blockIdx.z;
  const _Float16* Ap = Ag + (long)z * sA + (long)m0 * lda;
  const _Float16* Bp = Btg + (long)(z / zdivB) * sB + (long)n0 * ldb;
  const int wr = wid >> 1, wc = wid & 1;
  const int lrow = lane & 15, kseg = lane >> 4;
  const int kl = causal ? ((m0 + BM < K) ? m0 + BM : K) : K;

  auto stage = [&](int b, int k0) {
    #pragma unroll
    for (int i = 0; i < BM / 64; ++i) {
      const int cbase = (i * 4 + wid) * 64;
      const int row = (cbase >> 2) + (lane >> 2);
      const int src = ((lane & 3) ^ ((row >> 1) & 3)) * 8;
      gload16(Ap + (long)row * lda + k0 + src, (char*)As[b] + cbase * 16);
    }
    #pragma unroll
    for (int i = 0; i < 2; ++i) {
      const int cbase = (i * 4 + wid) * 64;
      const int row = (cbase >> 2) + (lane >> 2);
      const int src = ((lane & 3) ^ ((row >> 1) & 3)) * 8;
      gload16(Bp + (long)row * ldb + k0 + src, (char*)Bs[b] + cbase * 16);
    }
  };

  const int nt = kl >> 5;
  f32x4 acc[MR][4] = {};
  stage(0, 0);
  if (nt > 1) stage(1, 32);
  for (int t = 0; t < nt; ++t) {
    if (t + 2 < nt) {
      stage((t + 2) % 3, (t + 2) * 32);
      if constexpr (BM == 128) asm volatile("s_waitcnt vmcnt(8)" ::: "memory");
      else                     asm volatile("s_waitcnt vmcnt(6)" ::: "memory");
    } else if (t + 1 < nt) {
      if constexpr (BM == 128) asm volatile("s_waitcnt vmcnt(4)" ::: "memory");
      else                     asm volatile("s_waitcnt vmcnt(3)" ::: "memory");
    } else {
      asm volatile("s_waitcnt vmcnt(0)" ::: "memory");
    }
    __builtin_amdgcn_s_barrier();
    __builtin_amdgcn_sched_barrier(0);
    const int buf = t % 3;
    f16x8 fa[MR], fb[4];
    #pragma unroll
    for (int m = 0; m < MR; ++m) {
      const int row = wr * (BM / 2) + m * 16 + lrow;
      fa[m] = *(const f16x8*)&As[buf][row * 32 + ((kseg ^ ((row >> 1) & 3)) << 3)];
    }
    #pragma unroll
    for (int n = 0; n < 4; ++n) {
      const int row = wc * 64 + n * 16 + lrow;
      fb[n] = *(const f16x8*)&Bs[buf][row * 32 + ((kseg ^ ((row >> 1) & 3)) << 3)];
    }
    #pragma unroll
    for (int m = 0; m < MR; ++m)
      #pragma unroll
      for (int n = 0; n < 4; ++n)
        acc[m][n] = __builtin_amdgcn_mfma_f32_16x16x32_f16(fa[m], fb[n], acc[m][n], 0, 0, 0);
    __builtin_amdgcn_s_barrier();
  }
  CT* Cp = Cg + (long)z * sC;
  #pragma unroll
  for (int m = 0; m < MR; ++m)
    #pragma unroll
    for (int n = 0; n < 4; ++n)
      #pragma unroll
      for (int i = 0; i < 4; ++i) {
        const int r = m0 + wr * (BM / 2) + m * 16 + kseg * 4 + i;  // row=(lane>>4)*4+i (m89)
        const int c = n0 + wc * 64 + n * 16 + lrow;                // col=lane&15
        Cp[(long)r * ldc + c] = (CT)acc[m][n][i];
      }
}

// ---------------------------------------------------------------------------
// Per (b,h): logsigmoid, cumsum cf, a = i_pre - cf, running max m, vecM = cf+m.
// ---------------------------------------------------------------------------
__global__ __launch_bounds__(1024) void gates_kernel(
    const float* __restrict__ fp, const float* __restrict__ ip,
    float* __restrict__ aArr, float* __restrict__ mArr, float* __restrict__ vMArr)
{
  const int bh = blockIdx.x;
  const int s = threadIdx.x;
  __shared__ float sh[1024];
  const float f = fp[(long)bh * S_LEN + s];
  const float lsg = fminf(f, 0.0f) - log1pf(expf(-fabsf(f)));  // log_sigmoid
  float v = lsg;
  sh[s] = v; __syncthreads();
  for (int off = 1; off < 1024; off <<= 1) {
    const float o = (s >= off) ? sh[s - off] : 0.0f;
    __syncthreads();
    v += o; sh[s] = v;
    __syncthreads();
  }
  const float cf = v;
  const float a = ip[(long)bh * S_LEN + s] - cf;
  v = a;
  sh[s] = v; __syncthreads();
  for (int off = 1; off < 1024; off <<= 1) {
    const float o = (s >= off) ? sh[s - off] : -3.0e38f;
    __syncthreads();
    v = fmaxf(v, o); sh[s] = v;
    __syncthreads();
  }
  aArr[(long)bh * S_LEN + s] = a;
  mArr[(long)bh * S_LEN + s] = v;
  vMArr[(long)bh * S_LEN + s] = cf + v;
}

// ---------------------------------------------------------------------------
// Fused mLSTM attention + LN + output gate, triangle-paired, QBLK=32,
// 512 threads / 8 waves.  R14: each block holds the COMPLETE h-rows for its
// 64 tokens (8 waves x 32 d = 256 d), so the per-head LN (mean/var over 256)
// is a cross-wave LDS reduction like invn.  Epilogue applies LN + gamma +
// sigmoid(o) and writes ub directly — ln_gate kernel and hb buffer deleted.
// ---------------------------------------------------------------------------
__global__ __launch_bounds__(512) void att_fused_kernel(
    const _Float16* __restrict__ qkvo, const _Float16* __restrict__ vt,
    const float* __restrict__ aArr, const float* __restrict__ mArr,
    const float* __restrict__ vMArr, const float* __restrict__ gamma,
    _Float16* __restrict__ ub)
{
  __shared__ _Float16 Qs[2][32 * 256];   // swizzled: 32 chunks/row, ^(row&7)
  __shared__ _Float16 Ws[2][32 * 128];   // swizzled: 16 chunks/row, ^((row&7)<<1)
  __shared__ float nsh[2][8][32];
  __shared__ float s2sh[2][8][32];
  __shared__ float invs[2][32];
  __shared__ float musl[2][32], rssl[2][32];
  const int tid = threadIdx.x;
  const int lane = tid & 63, wid = tid >> 6;     // 8 waves
  const int bh = blockIdx.y;
  const int b = bh >> 3, h = bh & 7;
  const int r0[2] = { (int)blockIdx.x * 32, (31 - (int)blockIdx.x) * 32 };
  const _Float16* Qg = qkvo + (long)(b * S_LEN) * NQKVO + h * DH_;
  const _Float16* Kg = qkvo + (long)(b * S_LEN) * NQKVO + 2048;
  const _Float16* Og = qkvo + (long)(b * S_LEN) * NQKVO + 2560 + h * DH_;
  const _Float16* Vt = vt + (long)b * DH_ * S_LEN;
  const float* aA = aArr + (long)bh * S_LEN;
  const float* mA = mArr + (long)bh * S_LEN;
  const float* gam = gamma + h * DH_;
  const int lrow = lane & 15, kseg = lane >> 4;
  const int tbase = 16 * wid;                    // QK t-slice per wave
  const int dbase = 32 * wid;                    // PV d-slice per wave

  #pragma unroll
  for (int i = 0; i < 4; ++i) {
    const int cbase = (i * 8 + wid) * 64;        // wave-uniform
    const int c = cbase + lane;
    const int sub = c >> 10, row = (c >> 5) & 31, slot = c & 31;
    gload16(Qg + (long)(r0[sub] + row) * NQKVO + (slot ^ (row & 7)) * 8,
            (char*)Qs + cbase * 16);
  }

  float m_s[2][2][4];
  #pragma unroll
  for (int sub = 0; sub < 2; ++sub)
    #pragma unroll
    for (int m = 0; m < 2; ++m)
      #pragma unroll
      for (int i = 0; i < 4; ++i)
        m_s[sub][m][i] = mA[r0[sub] + m * 16 + kseg * 4 + i];
  __syncthreads();   // Q staged (drains vmcnt)

  f32x4 hacc[2][2][2] = {};
  float nacc[2][2][4] = {};
  for (int n0 = 0; n0 <= r0[1]; n0 += 128) {
    // ---- QK^T: 1 K-frag per wave (16 t-cols), next-step reg prefetch ----
    f32x4 acc[2][2] = {};
    f16x8 fb, fbn;
    fb = *(const f16x8*)(Kg + (long)(n0 + tbase + lrow) * NQKVO + kseg * 8);
    #pragma unroll
    for (int k0 = 0; k0 < DH_; k0 += 32) {
      if (k0 + 32 < DH_)
        fbn = *(const f16x8*)(Kg + (long)(n0 + tbase + lrow) * NQKVO + k0 + 32 + kseg * 8);
      const int chunk = (k0 >> 3) + kseg;
      __builtin_amdgcn_s_setprio(1);
      #pragma unroll
      for (int sub = 0; sub < 2; ++sub) {
        if (n0 > r0[sub]) continue;
        #pragma unroll
        for (int m = 0; m < 2; ++m) {
          const int qrow = m * 16 + lrow;
          const f16x8 fa = *(const f16x8*)&Qs[sub][qrow * 256 + ((chunk ^ (qrow & 7)) << 3)];
          acc[sub][m] = __builtin_amdgcn_mfma_f32_16x16x32_f16(fa, fb, acc[sub][m], 0, 0, 0);
        }
      }
      __builtin_amdgcn_s_setprio(0);
      fb = fbn;
    }
    // ---- weighting -> Ws (swizzled), row-sum accumulation ----
    const float a_t = aA[n0 + tbase + lrow];
    #pragma unroll
    for (int sub = 0; sub < 2; ++sub) {
      if (n0 > r0[sub]) continue;
      #pragma unroll
      for (int m = 0; m < 2; ++m)
        #pragma unroll
        for (int i = 0; i < 4; ++i) {
          const int sr = m * 16 + kseg * 4 + i;     // local row 0..31
          const int t  = tbase + lrow;              // local col 0..127
          float w = 0.0f;
          if (n0 + t <= r0[sub] + sr)
            w = acc[sub][m][i] * 0.0625f * expf(a_t - m_s[sub][m][i]);
          nacc[sub][m][i] += w;
          Ws[sub][sr * 128 + (((t >> 3) ^ ((sr & 7) << 1)) << 3) + (t & 7)] = f2h(w);
        }
    }
    // ---- issue-early V loads for kt=0 ----
    f16x8 vb[2], vbn[2];
    #pragma unroll
    for (int n = 0; n < 2; ++n)
      vb[n] = *(const f16x8*)(Vt + (long)(dbase + n * 16 + lrow) * S_LEN + n0 + kseg * 8);
    __syncthreads();
    // ---- PV: Ws from LDS, V frags pipelined ----
    #pragma unroll
    for (int kt = 0; kt < 128; kt += 32) {
      if (kt + 32 < 128) {
        #pragma unroll
        for (int n = 0; n < 2; ++n)
          vbn[n] = *(const f16x8*)(Vt + (long)(dbase + n * 16 + lrow) * S_LEN + n0 + kt + 32 + kseg * 8);
      }
      const int chunk = (kt >> 3) + kseg;
      __builtin_amdgcn_s_setprio(1);
      #pragma unroll
      for (int sub = 0; sub < 2; ++sub) {
        if (n0 > r0[sub]) continue;
        #pragma unroll
        for (int m = 0; m < 2; ++m) {
          const int row = m * 16 + lrow;
          const f16x8 wa = *(const f16x8*)&Ws[sub][row * 128 + ((chunk ^ ((row & 7) << 1)) << 3)];
          #pragma unroll
          for (int n = 0; n < 2; ++n)
            hacc[sub][m][n] = __builtin_amdgcn_mfma_f32_16x16x32_f16(wa, vb[n], hacc[sub][m][n], 0, 0, 0);
        }
      }
      __builtin_amdgcn_s_setprio(0);
      vb[0] = vbn[0]; vb[1] = vbn[1];
    }
    __syncthreads();   // Ws reads done before next pass overwrites
  }
  // ---- row sums -> invn ----
  #pragma unroll
  for (int sub = 0; sub < 2; ++sub)
    #pragma unroll
    for (int m = 0; m < 2; ++m)
      #pragma unroll
      for (int i = 0; i < 4; ++i) {
        float v = nacc[sub][m][i];
        v += __shfl_xor(v, 1); v += __shfl_xor(v, 2);
        v += __shfl_xor(v, 4); v += __shfl_xor(v, 8);
        if (lrow == 0) nsh[sub][wid][m * 16 + kseg * 4 + i] = v;
      }
  __syncthreads();
  if (tid < 64) {
    const int sub = tid >> 5, sr = tid & 31;
    float tot = 0.0f;
    #pragma unroll
    for (int w = 0; w < 8; ++w) tot += nsh[sub][w][sr];
    const float vm = vMArr[(long)bh * S_LEN + r0[sub] + sr];
    const float vecN = fmaxf(fabsf(tot), expf(-vm));
    invs[sub][sr] = 1.0f / (vecN + 1e-6f);
  }
  __syncthreads();
  // ---- fused LN: scale by invn, per-row sum/sumsq over d (shfl + LDS) ----
  #pragma unroll
  for (int sub = 0; sub < 2; ++sub)
    #pragma unroll
    for (int m = 0; m < 2; ++m)
      #pragma unroll
      for (int i = 0; i < 4; ++i) {
        const int row = m * 16 + kseg * 4 + i;
        const float inv = invs[sub][row];
        hacc[sub][m][0][i] *= inv;
        hacc[sub][m][1][i] *= inv;
        float s1 = hacc[sub][m][0][i] + hacc[sub][m][1][i];
        float s2 = hacc[sub][m][0][i] * hacc[sub][m][0][i]
                 + hacc[sub][m][1][i] * hacc[sub][m][1][i];
        s1 += __shfl_xor(s1, 1); s2 += __shfl_xor(s2, 1);
        s1 += __shfl_xor(s1, 2); s2 += __shfl_xor(s2, 2);
        s1 += __shfl_xor(s1, 4); s2 += __shfl_xor(s2, 4);
        s1 += __shfl_xor(s1, 8); s2 += __shfl_xor(s2, 8);
        if (lrow == 0) { nsh[sub][wid][row] = s1; s2sh[sub][wid][row] = s2; }
      }
  __syncthreads();
  if (tid < 64) {
    const int sub = tid >> 5, sr = tid & 31;
    float s1 = 0.0f, s2 = 0.0f;
    #pragma unroll
    for (int w = 0; w < 8; ++w) { s1 += nsh[sub][w][sr]; s2 += s2sh[sub][w][sr]; }
    const float mu = s1 * (1.0f / 256.0f);
    const float var = s2 * (1.0f / 256.0f) - mu * mu;
    musl[sub][sr] = mu;
    rssl[sub][sr] = rsqrtf(var + 1e-6f);
  }
  __syncthreads();
  // ---- apply LN + gamma + sigmoid(o), write ub ----
  #pragma unroll
  for (int sub = 0; sub < 2; ++sub)
    #pragma unroll
    for (int m = 0; m < 2; ++m)
      #pragma unroll
      for (int n = 0; n < 2; ++n)
        #pragma unroll
        for (int i = 0; i < 4; ++i) {
          const int row = m * 16 + kseg * 4 + i;
          const int d = dbase + n * 16 + lrow;
          const long gr = r0[sub] + row;
          const float hn = (hacc[sub][m][n][i] - musl[sub][row]) * rssl[sub][row] * gam[d];
          const float o = (float)Og[((long)gr) * NQKVO + d];
          ub[(long)(b * S_LEN + gr) * EMB + h * DH_ + d] =
              f2h(hn * (1.0f / (1.0f + expf(-o))));
        }
}

// ---------------------------------------------------------------------------
extern "C" void kernel_launch(void* const* d_in, const int* in_sizes, int n_in,
                              void* d_out, int out_size, void* d_ws, size_t ws_size,
                              hipStream_t stream)
{
  (void)in_sizes; (void)n_in; (void)out_size; (void)ws_size;
  const float* x     = (const float*)d_in[0];
  const float* Wq    = (const float*)d_in[1];
  const float* Wk    = (const float*)d_in[2];
  const float* Wv    = (const float*)d_in[3];
  const float* Wog   = (const float*)d_in[4];
  const float* Wi    = (const float*)d_in[5];
  const float* bi    = (const float*)d_in[6];
  const float* Wf    = (const float*)d_in[7];
  const float* bfg   = (const float*)d_in[8];
  const float* gamma = (const float*)d_in[9];
  const float* Wout  = (const float*)d_in[10];

  char* base = (char*)d_ws;
  size_t off = 0;
  auto take = [&](size_t bytes) -> char* {
    char* p = base + off;
    off += (bytes + 255) & ~(size_t)255;
    return p;
  };
  _Float16* xh    = (_Float16*)take((size_t)TOKENS * EMB * 2);        //  8 MB
  _Float16* WcatT = (_Float16*)take((size_t)NQKVO * EMB * 2);         // 19 MB
  _Float16* WoutT = (_Float16*)take((size_t)EMB * EMB * 2);           //  8 MB
  _Float16* qkvo  = (_Float16*)take((size_t)TOKENS * NQKVO * 2);      // 19 MB
  _Float16* vt    = (_Float16*)take((size_t)2 * DH_ * S_LEN * 2);     //  1 MB
  _Float16* ub    = (_Float16*)take((size_t)TOKENS * EMB * 2);        //  8 MB
  float*    ip    = (float*)take((size_t)NBH * S_LEN * 4);
  float*    fp    = (float*)take((size_t)NBH * S_LEN * 4);
  float*    aA    = (float*)take((size_t)NBH * S_LEN * 4);
  float*    mA    = (float*)take((size_t)NBH * S_LEN * 4);
  float*    vM    = (float*)take((size_t)NBH * S_LEN * 4);
  float*    y     = (float*)d_out;

  const dim3 blk(256);
  // --- merged prep: x cast + i/f projections + all weight transposes ---
  prep_kernel<<<dim3(TOKENS + 3328), blk, 0, stream>>>(
      x, Wi, bi, Wf, bfg, Wq, Wk, Wv, Wog, Wout, xh, ip, fp, WcatT, WoutT);
  // --- fused QKVO projection: [2048,4608] = xh @ WcatT^T (576 blocks) ---
  gemm_bt_kernel<_Float16, 128><<<dim3(36 * 16), blk, 0, stream>>>(
      xh, WcatT, qkvo, EMB, EMB, EMB, NQKVO, 0L, 0L, 0L, 1, 16, 0);
  // --- V^T per batch ---
  transpose_cast_kernel<_Float16><<<dim3(4, 16, 2), blk, 0, stream>>>(
      qkvo + 2304, NQKVO, vt, S_LEN, (long)S_LEN * NQKVO, (long)DH_ * S_LEN);
  // --- gates ---
  gates_kernel<<<dim3(NBH), dim3(1024), 0, stream>>>(fp, ip, aA, mA, vM);
  // --- fused mLSTM backend + LN + output gate (writes ub directly) ---
  att_fused_kernel<<<dim3(16, NBH), dim3(512), 0, stream>>>(
      qkvo, vt, aA, mA, vM, gamma, ub);
  // --- output projection: BM=64, 512 blocks -> 4 blocks/CU ---
  gemm_bt_kernel<float, 64><<<dim3(32 * 16), blk, 0, stream>>>(
      ub, WoutT, y, EMB, EMB, EMB, EMB, 0L, 0L, 0L, 1, 32, 0);
}

// Round 15
// 175.278 us; speedup vs baseline: 1.0445x; 1.0226x over previous
//
#include <hip/hip_runtime.h>
#include <math.h>

#define S_LEN  1024
#define EMB    2048
#define NH_    8
#define DH_    256
#define TOKENS 2048   // B*S
#define NBH    16     // B*NH
#define NQKVO  4608   // 2048 q | 256 k | 256 v | 2048 o

typedef __attribute__((ext_vector_type(4))) float    f32x4;
typedef __attribute__((ext_vector_type(8))) _Float16 f16x8;
typedef __attribute__((ext_vector_type(4))) _Float16 f16x4;

__device__ __forceinline__ _Float16 f2h(float f) { return (_Float16)f; }

// async global->LDS, 16B per lane; LDS dest = wave-uniform base + lane*16
__device__ __forceinline__ void gload16(const void* g, void* l) {
  __builtin_amdgcn_global_load_lds(
      (const __attribute__((address_space(1))) void*)g,
      (__attribute__((address_space(3))) void*)l, 16, 0, 0);
}

// ---------------------------------------------------------------------------
// Merged prep: blocks [0,2048): x->xh cast + i/f gate projections;
// blocks [2048,5376): weight transposes (Wq,Wk,Wv,Wog->WcatT; Wout->WoutT).
// ---------------------------------------------------------------------------
__global__ __launch_bounds__(256) void prep_kernel(
    const float* __restrict__ x, const float* __restrict__ Wi, const float* __restrict__ bi,
    const float* __restrict__ Wf, const float* __restrict__ bfg,
    const float* __restrict__ Wq, const float* __restrict__ Wk,
    const float* __restrict__ Wv, const float* __restrict__ Wog,
    const float* __restrict__ Wout,
    _Float16* __restrict__ xh, float* __restrict__ ip, float* __restrict__ fp,
    _Float16* __restrict__ WcatT, _Float16* __restrict__ WoutT)
{
  __shared__ float shmem[64][65];
  int t = blockIdx.x;
  const int tid = threadIdx.x;
  if (t < TOKENS) {
    // ---- proj_if_cast ----
    const int tok = t;
    const float* xr = x + (long)tok * EMB;
    float ai[8] = {}, af[8] = {};
    #pragma unroll
    for (int j = 0; j < 8; ++j) {
      const int e = tid + j * 256;
      const float xe = xr[e];
      xh[(long)tok * EMB + e] = f2h(xe);
      const float4* wi4 = (const float4*)(Wi + (long)e * 8);
      const float4* wf4 = (const float4*)(Wf + (long)e * 8);
      const float4 a0 = wi4[0], a1 = wi4[1], b0 = wf4[0], b1 = wf4[1];
      ai[0] += xe * a0.x; ai[1] += xe * a0.y; ai[2] += xe * a0.z; ai[3] += xe * a0.w;
      ai[4] += xe * a1.x; ai[5] += xe * a1.y; ai[6] += xe * a1.z; ai[7] += xe * a1.w;
      af[0] += xe * b0.x; af[1] += xe * b0.y; af[2] += xe * b0.z; af[3] += xe * b0.w;
      af[4] += xe * b1.x; af[5] += xe * b1.y; af[6] += xe * b1.z; af[7] += xe * b1.w;
    }
    #pragma unroll
    for (int hh = 0; hh < 8; ++hh)
      for (int off = 32; off; off >>= 1) {
        ai[hh] += __shfl_xor(ai[hh], off);
        af[hh] += __shfl_xor(af[hh], off);
      }
    float (*red)[16] = (float(*)[16])shmem;
    const int lane = tid & 63, wid = tid >> 6;
    if (lane == 0) {
      #pragma unroll
      for (int hh = 0; hh < 8; ++hh) { red[wid][hh] = ai[hh]; red[wid][hh + 8] = af[hh]; }
    }
    __syncthreads();
    if (tid < 16) {
      const float v = red[0][tid] + red[1][tid] + red[2][tid] + red[3][tid];
      const int b = tok >> 10, s = tok & 1023;
      if (tid < 8) {
        const float zv = v + bi[tid];
        ip[(long)(b * NH_ + tid) * S_LEN + s] = 15.0f * tanhf(zv * (1.0f / 15.0f));
      } else {
        const int hh = tid - 8;
        const float zv = v + bfg[hh];
        fp[(long)(b * NH_ + hh) * S_LEN + s] = 15.0f * tanhf(zv * (1.0f / 15.0f));
      }
    }
  } else {
    // ---- weight transposes ----
    t -= TOKENS;
    const float* in; _Float16* out; int ldi, ct;
    if (t < 1024)      { in = Wq;   out = WcatT;                    ldi = 2048; ct = 32; }
    else if (t < 1152) { t -= 1024; in = Wk;  out = WcatT + (long)2048 * EMB; ldi = 256; ct = 4; }
    else if (t < 1280) { t -= 1152; in = Wv;  out = WcatT + (long)2304 * EMB; ldi = 256; ct = 4; }
    else if (t < 2304) { t -= 1280; in = Wog; out = WcatT + (long)2560 * EMB; ldi = 2048; ct = 32; }
    else               { t -= 2304; in = Wout; out = WoutT;         ldi = 2048; ct = 32; }
    const long c0 = (long)(t % ct) * 64, r0 = (long)(t / ct) * 64;
    const int lx = tid & 63, ly = tid >> 6;
    #pragma unroll
    for (int i = 0; i < 16; ++i)
      shmem[ly + i * 4][lx] = in[(r0 + ly + i * 4) * ldi + c0 + lx];
    __syncthreads();
    #pragma unroll
    for (int i = 0; i < 16; ++i)
      out[(c0 + ly + i * 4) * EMB + r0 + lx] = f2h(shmem[lx][ly + i * 4]);
  }
}

// ---------------------------------------------------------------------------
// f16 GEMM, BMx128 tile, BK=32, 4 waves, 3-deep prefetch (R12 proven loop:
// stage BEFORE vmcnt wait, two barriers).  XOR-swizzled LDS; XCD swizzle.
// ---------------------------------------------------------------------------
template<typename CT, int BM>
__global__ __launch_bounds__(256) void gemm_bt_kernel(
    const _Float16* __restrict__ Ag, const _Float16* __restrict__ Btg,
    CT* __restrict__ Cg, int K, int lda, int ldb, int ldc,
    long sA, long sB, long sC, int zdivB, int mtiles, int causal)
{
  constexpr int MR = BM / 32;
  __shared__ _Float16 As[3][BM * 32];
  __shared__ _Float16 Bs[3][128 * 32];
  const int tid = threadIdx.x;
  const int lane = tid & 63, wid = tid >> 6;
  const int cpx = gridDim.x >> 3;
  const int wg = ((int)blockIdx.x & 7) * cpx + ((int)blockIdx.x >> 3);
  const int m0 = (wg % mtiles) * BM;
  const int n0 = (wg / mtiles) * 128;
  const int z  = blockIdx.z;
  const _Float16* Ap = Ag + (long)z * sA + (long)m0 * lda;
  const _Float16* Bp = Btg + (long)(z / zdivB) * sB + (long)n0 * ldb;
  const int wr = wid >> 1, wc = wid & 1;
  const int lrow = lane & 15, kseg = lane >> 4;
  const int kl = causal ? ((m0 + BM < K) ? m0 + BM : K) : K;

  auto stage = [&](int b, int k0) {
    #pragma unroll
    for (int i = 0; i < BM / 64; ++i) {
      const int cbase = (i * 4 + wid) * 64;
      const int row = (cbase >> 2) + (lane >> 2);
      const int src = ((lane & 3) ^ ((row >> 1) & 3)) * 8;
      gload16(Ap + (long)row * lda + k0 + src, (char*)As[b] + cbase * 16);
    }
    #pragma unroll
    for (int i = 0; i < 2; ++i) {
      const int cbase = (i * 4 + wid) * 64;
      const int row = (cbase >> 2) + (lane >> 2);
      const int src = ((lane & 3) ^ ((row >> 1) & 3)) * 8;
      gload16(Bp + (long)row * ldb + k0 + src, (char*)Bs[b] + cbase * 16);
    }
  };

  const int nt = kl >> 5;
  f32x4 acc[MR][4] = {};
  stage(0, 0);
  if (nt > 1) stage(1, 32);
  for (int t = 0; t < nt; ++t) {
    if (t + 2 < nt) {
      stage((t + 2) % 3, (t + 2) * 32);
      if constexpr (BM == 128) asm volatile("s_waitcnt vmcnt(8)" ::: "memory");
      else                     asm volatile("s_waitcnt vmcnt(6)" ::: "memory");
    } else if (t + 1 < nt) {
      if constexpr (BM == 128) asm volatile("s_waitcnt vmcnt(4)" ::: "memory");
      else                     asm volatile("s_waitcnt vmcnt(3)" ::: "memory");
    } else {
      asm volatile("s_waitcnt vmcnt(0)" ::: "memory");
    }
    __builtin_amdgcn_s_barrier();
    __builtin_amdgcn_sched_barrier(0);
    const int buf = t % 3;
    f16x8 fa[MR], fb[4];
    #pragma unroll
    for (int m = 0; m < MR; ++m) {
      const int row = wr * (BM / 2) + m * 16 + lrow;
      fa[m] = *(const f16x8*)&As[buf][row * 32 + ((kseg ^ ((row >> 1) & 3)) << 3)];
    }
    #pragma unroll
    for (int n = 0; n < 4; ++n) {
      const int row = wc * 64 + n * 16 + lrow;
      fb[n] = *(const f16x8*)&Bs[buf][row * 32 + ((kseg ^ ((row >> 1) & 3)) << 3)];
    }
    #pragma unroll
    for (int m = 0; m < MR; ++m)
      #pragma unroll
      for (int n = 0; n < 4; ++n)
        acc[m][n] = __builtin_amdgcn_mfma_f32_16x16x32_f16(fa[m], fb[n], acc[m][n], 0, 0, 0);
    __builtin_amdgcn_s_barrier();
  }
  CT* Cp = Cg + (long)z * sC;
  #pragma unroll
  for (int m = 0; m < MR; ++m)
    #pragma unroll
    for (int n = 0; n < 4; ++n)
      #pragma unroll
      for (int i = 0; i < 4; ++i) {
        const int r = m0 + wr * (BM / 2) + m * 16 + kseg * 4 + i;  // row=(lane>>4)*4+i (m89)
        const int c = n0 + wc * 64 + n * 16 + lrow;                // col=lane&15
        Cp[(long)r * ldc + c] = (CT)acc[m][n][i];
      }
}

// ---------------------------------------------------------------------------
// Merged mid stage (one launch): blocks [0,16): gates (wave-scan version);
// blocks [16,144): V^T transpose (f16).
// Gates: 256 threads, 4 consecutive s per thread.  Inclusive cumsum of
// logsigmoid(f) and running max of a = i - cf via per-thread chunk +
// __shfl_up wave scan + one LDS cross-wave pass (2 barriers total, vs ~40
// in the old 1024-thread Hillis-Steele).
// ---------------------------------------------------------------------------
__global__ __launch_bounds__(256) void mid_kernel(
    const _Float16* __restrict__ qkvo, _Float16* __restrict__ vt,
    const float* __restrict__ fp, const float* __restrict__ ip,
    float* __restrict__ aArr, float* __restrict__ mArr, float* __restrict__ vMArr)
{
  __shared__ float shmem[64][65];
  const int tid = threadIdx.x;
  int t = blockIdx.x;
  if (t < NBH) {
    const int bh = t;
    const int lane = tid & 63, wid = tid >> 6;
    float* wsum = &shmem[0][0];   // [4]
    float* wmax = &shmem[1][0];   // [4]
    const int s4 = tid * 4;
    const float4 fv = *(const float4*)(fp + (long)bh * S_LEN + s4);
    const float4 iv = *(const float4*)(ip + (long)bh * S_LEN + s4);
    float lg[4];
    lg[0] = fminf(fv.x, 0.0f) - log1pf(expf(-fabsf(fv.x)));
    lg[1] = fminf(fv.y, 0.0f) - log1pf(expf(-fabsf(fv.y)));
    lg[2] = fminf(fv.z, 0.0f) - log1pf(expf(-fabsf(fv.z)));
    lg[3] = fminf(fv.w, 0.0f) - log1pf(expf(-fabsf(fv.w)));
    // local inclusive sums
    float c0 = lg[0], c1 = c0 + lg[1], c2 = c1 + lg[2], c3 = c2 + lg[3];
    // wave inclusive scan of per-thread totals
    float ts = c3;
    #pragma unroll
    for (int off = 1; off < 64; off <<= 1) {
      const float o = __shfl_up(ts, off);
      if (lane >= off) ts += o;
    }
    const float texcl = ts - c3;
    if (lane == 63) wsum[wid] = ts;
    __syncthreads();
    float woff = 0.0f;
    for (int w = 0; w < wid; ++w) woff += wsum[w];
    const float base = woff + texcl;
    const float cf[4] = { base + c0, base + c1, base + c2, base + c3 };
    const float a[4] = { iv.x - cf[0], iv.y - cf[1], iv.z - cf[2], iv.w - cf[3] };
    // running max of a
    float l0 = a[0], l1 = fmaxf(l0, a[1]), l2 = fmaxf(l1, a[2]), l3 = fmaxf(l2, a[3]);
    float incl = l3;
    #pragma unroll
    for (int off = 1; off < 64; off <<= 1) {
      const float o = __shfl_up(incl, off);
      if (lane >= off) incl = fmaxf(incl, o);
    }
    float excl = __shfl_up(incl, 1);
    if (lane == 0) excl = -3.0e38f;
    if (lane == 63) wmax[wid] = incl;
    __syncthreads();
    float wpre = -3.0e38f;
    for (int w = 0; w < wid; ++w) wpre = fmaxf(wpre, wmax[w]);
    const float pre = fmaxf(wpre, excl);
    float mm[4];
    mm[0] = fmaxf(pre, a[0]); mm[1] = fmaxf(mm[0], a[1]);
    mm[2] = fmaxf(mm[1], a[2]); mm[3] = fmaxf(mm[2], a[3]);
    float4 av = { a[0], a[1], a[2], a[3] };
    float4 mv = { mm[0], mm[1], mm[2], mm[3] };
    float4 vv = { cf[0] + mm[0], cf[1] + mm[1], cf[2] + mm[2], cf[3] + mm[3] };
    *(float4*)(aArr + (long)bh * S_LEN + s4) = av;
    *(float4*)(mArr + (long)bh * S_LEN + s4) = mv;
    *(float4*)(vMArr + (long)bh * S_LEN + s4) = vv;
  } else {
    // ---- V^T transpose: qkvo v-cols [2304,2560) -> vt[b][d][s] ----
    t -= NBH;
    const int z = t >> 6, rem = t & 63;
    const long c0 = (long)(rem & 3) * 64;    // d-tile
    const long r0 = (long)(rem >> 2) * 64;   // s-tile
    const _Float16* ipt = qkvo + (long)z * S_LEN * NQKVO + 2304;
    _Float16* op = vt + (long)z * DH_ * S_LEN;
    const int lx = tid & 63, ly = tid >> 6;
    #pragma unroll
    for (int i = 0; i < 16; ++i)
      shmem[ly + i * 4][lx] = (float)ipt[(r0 + ly + i * 4) * NQKVO + c0 + lx];
    __syncthreads();
    #pragma unroll
    for (int i = 0; i < 16; ++i)
      op[(c0 + ly + i * 4) * S_LEN + r0 + lx] = f2h(shmem[lx][ly + i * 4]);
  }
}

// ---------------------------------------------------------------------------
// Fused mLSTM attention + LN + output gate, triangle-paired, QBLK=32,
// 512 threads / 8 waves (R11/R14 config).
// ---------------------------------------------------------------------------
__global__ __launch_bounds__(512) void att_fused_kernel(
    const _Float16* __restrict__ qkvo, const _Float16* __restrict__ vt,
    const float* __restrict__ aArr, const float* __restrict__ mArr,
    const float* __restrict__ vMArr, const float* __restrict__ gamma,
    _Float16* __restrict__ ub)
{
  __shared__ _Float16 Qs[2][32 * 256];   // swizzled: 32 chunks/row, ^(row&7)
  __shared__ _Float16 Ws[2][32 * 128];   // swizzled: 16 chunks/row, ^((row&7)<<1)
  __shared__ float nsh[2][8][32];
  __shared__ float s2sh[2][8][32];
  __shared__ float invs[2][32];
  __shared__ float musl[2][32], rssl[2][32];
  const int tid = threadIdx.x;
  const int lane = tid & 63, wid = tid >> 6;     // 8 waves
  const int bh = blockIdx.y;
  const int b = bh >> 3, h = bh & 7;
  const int r0[2] = { (int)blockIdx.x * 32, (31 - (int)blockIdx.x) * 32 };
  const _Float16* Qg = qkvo + (long)(b * S_LEN) * NQKVO + h * DH_;
  const _Float16* Kg = qkvo + (long)(b * S_LEN) * NQKVO + 2048;
  const _Float16* Og = qkvo + (long)(b * S_LEN) * NQKVO + 2560 + h * DH_;
  const _Float16* Vt = vt + (long)b * DH_ * S_LEN;
  const float* aA = aArr + (long)bh * S_LEN;
  const float* mA = mArr + (long)bh * S_LEN;
  const float* gam = gamma + h * DH_;
  const int lrow = lane & 15, kseg = lane >> 4;
  const int tbase = 16 * wid;                    // QK t-slice per wave
  const int dbase = 32 * wid;                    // PV d-slice per wave

  #pragma unroll
  for (int i = 0; i < 4; ++i) {
    const int cbase = (i * 8 + wid) * 64;        // wave-uniform
    const int c = cbase + lane;
    const int sub = c >> 10, row = (c >> 5) & 31, slot = c & 31;
    gload16(Qg + (long)(r0[sub] + row) * NQKVO + (slot ^ (row & 7)) * 8,
            (char*)Qs + cbase * 16);
  }

  float m_s[2][2][4];
  #pragma unroll
  for (int sub = 0; sub < 2; ++sub)
    #pragma unroll
    for (int m = 0; m < 2; ++m)
      #pragma unroll
      for (int i = 0; i < 4; ++i)
        m_s[sub][m][i] = mA[r0[sub] + m * 16 + kseg * 4 + i];
  __syncthreads();   // Q staged (drains vmcnt)

  f32x4 hacc[2][2][2] = {};
  float nacc[2][2][4] = {};
  for (int n0 = 0; n0 <= r0[1]; n0 += 128) {
    // ---- QK^T: 1 K-frag per wave (16 t-cols), next-step reg prefetch ----
    f32x4 acc[2][2] = {};
    f16x8 fb, fbn;
    fb = *(const f16x8*)(Kg + (long)(n0 + tbase + lrow) * NQKVO + kseg * 8);
    #pragma unroll
    for (int k0 = 0; k0 < DH_; k0 += 32) {
      if (k0 + 32 < DH_)
        fbn = *(const f16x8*)(Kg + (long)(n0 + tbase + lrow) * NQKVO + k0 + 32 + kseg * 8);
      const int chunk = (k0 >> 3) + kseg;
      __builtin_amdgcn_s_setprio(1);
      #pragma unroll
      for (int sub = 0; sub < 2; ++sub) {
        if (n0 > r0[sub]) continue;
        #pragma unroll
        for (int m = 0; m < 2; ++m) {
          const int qrow = m * 16 + lrow;
          const f16x8 fa = *(const f16x8*)&Qs[sub][qrow * 256 + ((chunk ^ (qrow & 7)) << 3)];
          acc[sub][m] = __builtin_amdgcn_mfma_f32_16x16x32_f16(fa, fb, acc[sub][m], 0, 0, 0);
        }
      }
      __builtin_amdgcn_s_setprio(0);
      fb = fbn;
    }
    // ---- weighting -> Ws (swizzled), row-sum accumulation ----
    const float a_t = aA[n0 + tbase + lrow];
    #pragma unroll
    for (int sub = 0; sub < 2; ++sub) {
      if (n0 > r0[sub]) continue;
      #pragma unroll
      for (int m = 0; m < 2; ++m)
        #pragma unroll
        for (int i = 0; i < 4; ++i) {
          const int sr = m * 16 + kseg * 4 + i;     // local row 0..31
          const int t  = tbase + lrow;              // local col 0..127
          float w = 0.0f;
          if (n0 + t <= r0[sub] + sr)
            w = acc[sub][m][i] * 0.0625f * expf(a_t - m_s[sub][m][i]);
          nacc[sub][m][i] += w;
          Ws[sub][sr * 128 + (((t >> 3) ^ ((sr & 7) << 1)) << 3) + (t & 7)] = f2h(w);
        }
    }
    // ---- issue-early V loads for kt=0 ----
    f16x8 vb[2], vbn[2];
    #pragma unroll
    for (int n = 0; n < 2; ++n)
      vb[n] = *(const f16x8*)(Vt + (long)(dbase + n * 16 + lrow) * S_LEN + n0 + kseg * 8);
    __syncthreads();
    // ---- PV: Ws from LDS, V frags pipelined ----
    #pragma unroll
    for (int kt = 0; kt < 128; kt += 32) {
      if (kt + 32 < 128) {
        #pragma unroll
        for (int n = 0; n < 2; ++n)
          vbn[n] = *(const f16x8*)(Vt + (long)(dbase + n * 16 + lrow) * S_LEN + n0 + kt + 32 + kseg * 8);
      }
      const int chunk = (kt >> 3) + kseg;
      __builtin_amdgcn_s_setprio(1);
      #pragma unroll
      for (int sub = 0; sub < 2; ++sub) {
        if (n0 > r0[sub]) continue;
        #pragma unroll
        for (int m = 0; m < 2; ++m) {
          const int row = m * 16 + lrow;
          const f16x8 wa = *(const f16x8*)&Ws[sub][row * 128 + ((chunk ^ ((row & 7) << 1)) << 3)];
          #pragma unroll
          for (int n = 0; n < 2; ++n)
            hacc[sub][m][n] = __builtin_amdgcn_mfma_f32_16x16x32_f16(wa, vb[n], hacc[sub][m][n], 0, 0, 0);
        }
      }
      __builtin_amdgcn_s_setprio(0);
      vb[0] = vbn[0]; vb[1] = vbn[1];
    }
    __syncthreads();   // Ws reads done before next pass overwrites
  }
  // ---- row sums -> invn ----
  #pragma unroll
  for (int sub = 0; sub < 2; ++sub)
    #pragma unroll
    for (int m = 0; m < 2; ++m)
      #pragma unroll
      for (int i = 0; i < 4; ++i) {
        float v = nacc[sub][m][i];
        v += __shfl_xor(v, 1); v += __shfl_xor(v, 2);
        v += __shfl_xor(v, 4); v += __shfl_xor(v, 8);
        if (lrow == 0) nsh[sub][wid][m * 16 + kseg * 4 + i] = v;
      }
  __syncthreads();
  if (tid < 64) {
    const int sub = tid >> 5, sr = tid & 31;
    float tot = 0.0f;
    #pragma unroll
    for (int w = 0; w < 8; ++w) tot += nsh[sub][w][sr];
    const float vm = vMArr[(long)bh * S_LEN + r0[sub] + sr];
    const float vecN = fmaxf(fabsf(tot), expf(-vm));
    invs[sub][sr] = 1.0f / (vecN + 1e-6f);
  }
  __syncthreads();
  // ---- fused LN: scale by invn, per-row sum/sumsq over d (shfl + LDS) ----
  #pragma unroll
  for (int sub = 0; sub < 2; ++sub)
    #pragma unroll
    for (int m = 0; m < 2; ++m)
      #pragma unroll
      for (int i = 0; i < 4; ++i) {
        const int row = m * 16 + kseg * 4 + i;
        const float inv = invs[sub][row];
        hacc[sub][m][0][i] *= inv;
        hacc[sub][m][1][i] *= inv;
        float s1 = hacc[sub][m][0][i] + hacc[sub][m][1][i];
        float s2 = hacc[sub][m][0][i] * hacc[sub][m][0][i]
                 + hacc[sub][m][1][i] * hacc[sub][m][1][i];
        s1 += __shfl_xor(s1, 1); s2 += __shfl_xor(s2, 1);
        s1 += __shfl_xor(s1, 2); s2 += __shfl_xor(s2, 2);
        s1 += __shfl_xor(s1, 4); s2 += __shfl_xor(s2, 4);
        s1 += __shfl_xor(s1, 8); s2 += __shfl_xor(s2, 8);
        if (lrow == 0) { nsh[sub][wid][row] = s1; s2sh[sub][wid][row] = s2; }
      }
  __syncthreads();
  if (tid < 64) {
    const int sub = tid >> 5, sr = tid & 31;
    float s1 = 0.0f, s2 = 0.0f;
    #pragma unroll
    for (int w = 0; w < 8; ++w) { s1 += nsh[sub][w][sr]; s2 += s2sh[sub][w][sr]; }
    const float mu = s1 * (1.0f / 256.0f);
    const float var = s2 * (1.0f / 256.0f) - mu * mu;
    musl[sub][sr] = mu;
    rssl[sub][sr] = rsqrtf(var + 1e-6f);
  }
  __syncthreads();
  // ---- apply LN + gamma + sigmoid(o), write ub ----
  #pragma unroll
  for (int sub = 0; sub < 2; ++sub)
    #pragma unroll
    for (int m = 0; m < 2; ++m)
      #pragma unroll
      for (int n = 0; n < 2; ++n)
        #pragma unroll
        for (int i = 0; i < 4; ++i) {
          const int row = m * 16 + kseg * 4 + i;
          const int d = dbase + n * 16 + lrow;
          const long gr = r0[sub] + row;
          const float hn = (hacc[sub][m][n][i] - musl[sub][row]) * rssl[sub][row] * gam[d];
          const float o = (float)Og[((long)gr) * NQKVO + d];
          ub[(long)(b * S_LEN + gr) * EMB + h * DH_ + d] =
              f2h(hn * (1.0f / (1.0f + expf(-o))));
        }
}

// ---------------------------------------------------------------------------
extern "C" void kernel_launch(void* const* d_in, const int* in_sizes, int n_in,
                              void* d_out, int out_size, void* d_ws, size_t ws_size,
                              hipStream_t stream)
{
  (void)in_sizes; (void)n_in; (void)out_size; (void)ws_size;
  const float* x     = (const float*)d_in[0];
  const float* Wq    = (const float*)d_in[1];
  const float* Wk    = (const float*)d_in[2];
  const float* Wv    = (const float*)d_in[3];
  const float* Wog   = (const float*)d_in[4];
  const float* Wi    = (const float*)d_in[5];
  const float* bi    = (const float*)d_in[6];
  const float* Wf    = (const float*)d_in[7];
  const float* bfg   = (const float*)d_in[8];
  const float* gamma = (const float*)d_in[9];
  const float* Wout  = (const float*)d_in[10];

  char* base = (char*)d_ws;
  size_t off = 0;
  auto take = [&](size_t bytes) -> char* {
    char* p = base + off;
    off += (bytes + 255) & ~(size_t)255;
    return p;
  };
  _Float16* xh    = (_Float16*)take((size_t)TOKENS * EMB * 2);        //  8 MB
  _Float16* WcatT = (_Float16*)take((size_t)NQKVO * EMB * 2);         // 19 MB
  _Float16* WoutT = (_Float16*)take((size_t)EMB * EMB * 2);           //  8 MB
  _Float16* qkvo  = (_Float16*)take((size_t)TOKENS * NQKVO * 2);      // 19 MB
  _Float16* vt    = (_Float16*)take((size_t)2 * DH_ * S_LEN * 2);     //  1 MB
  _Float16* ub    = (_Float16*)take((size_t)TOKENS * EMB * 2);        //  8 MB
  float*    ip    = (float*)take((size_t)NBH * S_LEN * 4);
  float*    fp    = (float*)take((size_t)NBH * S_LEN * 4);
  float*    aA    = (float*)take((size_t)NBH * S_LEN * 4);
  float*    mA    = (float*)take((size_t)NBH * S_LEN * 4);
  float*    vM    = (float*)take((size_t)NBH * S_LEN * 4);
  float*    y     = (float*)d_out;

  const dim3 blk(256);
  // --- merged prep: x cast + i/f projections + all weight transposes ---
  prep_kernel<<<dim3(TOKENS + 3328), blk, 0, stream>>>(
      x, Wi, bi, Wf, bfg, Wq, Wk, Wv, Wog, Wout, xh, ip, fp, WcatT, WoutT);
  // --- fused QKVO projection: [2048,4608] = xh @ WcatT^T (576 blocks) ---
  gemm_bt_kernel<_Float16, 128><<<dim3(36 * 16), blk, 0, stream>>>(
      xh, WcatT, qkvo, EMB, EMB, EMB, NQKVO, 0L, 0L, 0L, 1, 16, 0);
  // --- merged mid: gates (wave-scan) + V^T transpose, one launch ---
  mid_kernel<<<dim3(NBH + 128), blk, 0, stream>>>(qkvo, vt, fp, ip, aA, mA, vM);
  // --- fused mLSTM backend + LN + output gate (writes ub directly) ---
  att_fused_kernel<<<dim3(16, NBH), dim3(512), 0, stream>>>(
      qkvo, vt, aA, mA, vM, gamma, ub);
  // --- output projection: BM=64, 512 blocks -> 4 blocks/CU ---
  gemm_bt_kernel<float, 64><<<dim3(32 * 16), blk, 0, stream>>>(
      ub, WoutT, y, EMB, EMB, EMB, EMB, 0L, 0L, 0L, 1, 32, 0);
}